// Round 3
// baseline (643.508 us; speedup 1.0000x reference)
//
#include <hip/hip_runtime.h>
#include <stdint.h>

#define Bb 8
#define Nn 256
#define Hh 768
#define Pp 128
#define HEADS 12
#define Dd 64
#define EPSf 1e-5f

typedef __attribute__((ext_vector_type(8))) short bhalf8;   // 8 bf16 (4 VGPRs)
typedef __attribute__((ext_vector_type(4))) float f32x4;

__device__ __forceinline__ unsigned short f2bf(float f) {
    union { float f; unsigned u; } v; v.f = f;
    unsigned r = v.u + 0x7FFFu + ((v.u >> 16) & 1u);
    return (unsigned short)(r >> 16);
}
// pack two floats -> two bf16 (round-half-up) in one perm
__device__ __forceinline__ unsigned pk(float lo, float hi) {
    unsigned a = __float_as_uint(lo) + 0x8000u;
    unsigned b = __float_as_uint(hi) + 0x8000u;
    return __builtin_amdgcn_perm(b, a, 0x07060302u);  // (bf(hi)<<16)|bf(lo)
}

// ---------------- K0a: 4x transpose fp32 [768][768] -> bf16 n-major ----------------
__global__ __launch_bounds__(256) void k_transpose4(const float* __restrict__ a0, const float* __restrict__ a1,
                                                    const float* __restrict__ a2, const float* __restrict__ a3,
                                                    unsigned short* __restrict__ o0, unsigned short* __restrict__ o1,
                                                    unsigned short* __restrict__ o2, unsigned short* __restrict__ o3) {
    __shared__ float tile[32][33];
    int z = blockIdx.z;
    const float* in = (z == 0) ? a0 : (z == 1) ? a1 : (z == 2) ? a2 : a3;
    unsigned short* out = (z == 0) ? o0 : (z == 1) ? o1 : (z == 2) ? o2 : o3;
    const int R = 768, C = 768;
    int c0 = blockIdx.x * 32, r0 = blockIdx.y * 32;
    int tx = threadIdx.x & 31, ty = threadIdx.x >> 5;
    for (int i = ty; i < 32; i += 8)
        tile[i][tx] = in[(size_t)(r0 + i) * C + c0 + tx];
    __syncthreads();
    for (int i = ty; i < 32; i += 8)
        out[(size_t)(c0 + i) * R + r0 + tx] = f2bf(tile[tx][i]);
}

// ---------------- K0b: 2x transpose fp32 [128][64] -> bf16 [64][128] ----------------
__global__ __launch_bounds__(256) void k_transpose_small(const float* __restrict__ a0, const float* __restrict__ a1,
                                                         unsigned short* __restrict__ o0, unsigned short* __restrict__ o1) {
    __shared__ float tile[32][33];
    int z = blockIdx.z;
    const float* in = (z == 0) ? a0 : a1;
    unsigned short* out = (z == 0) ? o0 : o1;
    const int R = 128, C = 64;
    int c0 = blockIdx.x * 32, r0 = blockIdx.y * 32;
    int tx = threadIdx.x & 31, ty = threadIdx.x >> 5;
    for (int i = ty; i < 32; i += 8)
        tile[i][tx] = in[(size_t)(r0 + i) * C + c0 + tx];
    __syncthreads();
    for (int i = ty; i < 32; i += 8)
        out[(size_t)(c0 + i) * R + r0 + tx] = f2bf(tile[tx][i]);
}

// ---------------- K1: QKV projection; dbuf-A, global-B, MFMA ----------------
__global__ __launch_bounds__(256) void k_qkv(const float* __restrict__ nodes,
                                             const unsigned short* __restrict__ Wt, // [2304][768] n-major
                                             const float* __restrict__ bqp, const float* __restrict__ bkp,
                                             const float* __restrict__ bvp,
                                             float* __restrict__ qso, float* __restrict__ kko,
                                             unsigned short* __restrict__ vvT) {
    __shared__ __align__(16) unsigned short A[2][64 * 72];
    int tid = threadIdx.x;
    int m0 = blockIdx.y * 64;
    int n0 = blockIdx.x * 128;
    int w = tid >> 6, lane = tid & 63;
    int wm = w >> 1, wn = w & 1;
    int lm = lane & 15, lq = lane >> 4;

    auto stageA = [&](int kt, unsigned short* dst) {
#pragma unroll
        for (int t = 0; t < 4; t++) {
            int c = t * 256 + tid;
            int row = c >> 4, cc = c & 15;
            float4 v = *(const float4*)(nodes + (size_t)(m0 + row) * 768 + kt + cc * 4);
            uint2 u; u.x = pk(v.x, v.y); u.y = pk(v.z, v.w);
            *(uint2*)(dst + row * 72 + cc * 4) = u;
        }
    };
    f32x4 acc[2][4];
#pragma unroll
    for (int i = 0; i < 2; i++)
#pragma unroll
        for (int j = 0; j < 4; j++) acc[i][j] = (f32x4){0.f, 0.f, 0.f, 0.f};

    stageA(0, A[0]);
    __syncthreads();
    int buf = 0;
    for (int kt = 0; kt < 768; kt += 64, buf ^= 1) {
        if (kt < 704) stageA(kt + 64, A[buf ^ 1]);
#pragma unroll
        for (int ks = 0; ks < 2; ks++) {
            bhalf8 af[2];
#pragma unroll
            for (int mi = 0; mi < 2; mi++)
                af[mi] = *(const bhalf8*)(A[buf] + (wm * 32 + mi * 16 + lm) * 72 + ks * 32 + lq * 8);
#pragma unroll
            for (int nt = 0; nt < 4; nt++) {
                bhalf8 bf = *(const bhalf8*)(Wt + (size_t)(n0 + wn * 64 + nt * 16 + lm) * 768 + kt + ks * 32 + lq * 8);
#pragma unroll
                for (int mi = 0; mi < 2; mi++)
                    acc[mi][nt] = __builtin_amdgcn_mfma_f32_16x16x32_bf16(af[mi], bf, acc[mi][nt], 0, 0, 0);
            }
        }
        __syncthreads();
    }
    int wsel = n0 / 768;
    int nb = n0 % 768;
    if (wsel == 2) {
        // V -> vvT bf16 [b][h][d][256 q]
#pragma unroll
        for (int mi = 0; mi < 2; mi++)
#pragma unroll
            for (int nt = 0; nt < 4; nt++) {
                int col = nb + wn * 64 + nt * 16 + lm;
                int h = col >> 6, d = col & 63;
                int row0 = m0 + wm * 32 + mi * 16 + lq * 4;
                int bb = row0 >> 8, q0 = row0 & 255;
                float bia = bvp[col];
                uint2 u;
                u.x = pk(acc[mi][nt][0] + bia, acc[mi][nt][1] + bia);
                u.y = pk(acc[mi][nt][2] + bia, acc[mi][nt][3] + bia);
                *(uint2*)(vvT + (((size_t)bb * HEADS + h) * Dd + d) * Nn + q0) = u;
            }
    } else {
        const float* bias = (wsel == 0) ? bqp : bkp;
        float* dst = (wsel == 0) ? qso : kko;
        float scale = (wsel == 0) ? 0.125f : 1.0f;
#pragma unroll
        for (int mi = 0; mi < 2; mi++)
#pragma unroll
            for (int nt = 0; nt < 4; nt++)
#pragma unroll
                for (int r = 0; r < 4; r++) {
                    int row = m0 + wm * 32 + mi * 16 + lq * 4 + r;
                    int col = nb + wn * 64 + nt * 16 + lm;
                    int hh = col >> 6, d = col & 63;
                    int bb = row >> 8, qn = row & 255;
                    float val = (acc[mi][nt][r] + bias[col]) * scale;
                    dst[(((size_t)bb * HEADS + hh) * Nn + qn) * Dd + d] = val;
                }
    }
}

// ---------------- K2: content scores + bias, MFMA ----------------
__global__ __launch_bounds__(256) void k_scores(const float* __restrict__ qs,
                                                const float* __restrict__ kk,
                                                const float* __restrict__ bias,
                                                float* __restrict__ wg) {
    __shared__ __align__(16) unsigned short Alds[64 * 72];
    __shared__ __align__(16) unsigned short Blds[64 * 72];
    int tid = threadIdx.x;
    int bh = blockIdx.z;
    int m0 = blockIdx.y * 64;
    int n0 = blockIdx.x * 64;
    int w = tid >> 6, lane = tid & 63, lm = lane & 15, lq = lane >> 4;
    const float* Abase = qs + ((size_t)bh * Nn + m0) * Dd;
    const float* Bbase = kk + ((size_t)bh * Nn + n0) * Dd;
#pragma unroll
    for (int t = 0; t < 4; t++) {
        int c = t * 256 + tid;
        int row = c >> 4, cc = c & 15;
        float4 va = *(const float4*)(Abase + (size_t)row * 64 + cc * 4);
        uint2 ua; ua.x = pk(va.x, va.y); ua.y = pk(va.z, va.w);
        *(uint2*)(Alds + row * 72 + cc * 4) = ua;
        float4 vb = *(const float4*)(Bbase + (size_t)row * 64 + cc * 4);
        uint2 ub; ub.x = pk(vb.x, vb.y); ub.y = pk(vb.z, vb.w);
        *(uint2*)(Blds + row * 72 + cc * 4) = ub;
    }
    __syncthreads();
    f32x4 acc[4];
#pragma unroll
    for (int i = 0; i < 4; i++) acc[i] = (f32x4){0.f, 0.f, 0.f, 0.f};
#pragma unroll
    for (int ks = 0; ks < 2; ks++) {
        bhalf8 af = *(const bhalf8*)(Alds + (w * 16 + lm) * 72 + ks * 32 + lq * 8);
#pragma unroll
        for (int nt = 0; nt < 4; nt++) {
            bhalf8 bf = *(const bhalf8*)(Blds + (nt * 16 + lm) * 72 + ks * 32 + lq * 8);
            acc[nt] = __builtin_amdgcn_mfma_f32_16x16x32_bf16(af, bf, acc[nt], 0, 0, 0);
        }
    }
#pragma unroll
    for (int nt = 0; nt < 4; nt++)
#pragma unroll
        for (int r = 0; r < 4; r++) {
            int row = m0 + w * 16 + lq * 4 + r;
            int col = n0 + nt * 16 + lm;
            size_t idx = ((size_t)bh * Nn + row) * Nn + col;
            wg[idx] = acc[nt][r] + bias[idx];
        }
}

// ---------------- K3: path LN + struct K/V proj; 128 rows/block, global-W ----------------
// outputs: skg[bq][k][64] bf16 ; svTg[bq][d][256] bf16
__global__ __launch_bounds__(256) void k_structproj(const float* __restrict__ paths,
                                                    const unsigned short* __restrict__ Wskvt, // [128 n][128 k]
                                                    const float* __restrict__ gp, const float* __restrict__ bp,
                                                    const float* __restrict__ bsk, const float* __restrict__ bsv,
                                                    unsigned short* __restrict__ skg,
                                                    unsigned short* __restrict__ svTg) {
    __shared__ __align__(16) unsigned short SM[17920];   // 35.84 KB
    unsigned short* pn  = SM;          // [128][136] LN'd paths
    unsigned short* skl = SM;          // [128][72]  (reuse after barrier)
    unsigned short* svl = SM + 9216;   // [64][136]
    int tid = threadIdx.x;
    size_t r0 = (size_t)blockIdx.x * 128;
    int bq = (int)(r0 >> 8), k0 = (int)(r0 & 255);
    int w = tid >> 6, lane = tid & 63, lm = lane & 15, lq = lane >> 4;
    float4 g0 = *(const float4*)(gp + lm * 4);
    float4 g1 = *(const float4*)(gp + 64 + lm * 4);
    float4 b0 = *(const float4*)(bp + lm * 4);
    float4 b1 = *(const float4*)(bp + 64 + lm * 4);
#pragma unroll
    for (int it = 0; it < 8; it++) {
        int row_l = w * 32 + it * 4 + lq;
        const float* pr = paths + (r0 + row_l) * 128;
        float4 x0 = *(const float4*)(pr + lm * 4);
        float4 x1 = *(const float4*)(pr + 64 + lm * 4);
        float s = (x0.x + x0.y) + (x0.z + x0.w) + (x1.x + x1.y) + (x1.z + x1.w);
        float s2 = x0.x * x0.x + x0.y * x0.y + x0.z * x0.z + x0.w * x0.w
                 + x1.x * x1.x + x1.y * x1.y + x1.z * x1.z + x1.w * x1.w;
#pragma unroll
        for (int mk = 1; mk < 16; mk <<= 1) {
            s += __shfl_xor(s, mk);
            s2 += __shfl_xor(s2, mk);
        }
        float mu = s * (1.f / 128.f);
        float var = s2 * (1.f / 128.f) - mu * mu;
        float rs = rsqrtf(var + EPSf);
        float p0 = (x0.x - mu) * rs * g0.x + b0.x;
        float p1 = (x0.y - mu) * rs * g0.y + b0.y;
        float p2 = (x0.z - mu) * rs * g0.z + b0.z;
        float p3 = (x0.w - mu) * rs * g0.w + b0.w;
        float p4 = (x1.x - mu) * rs * g1.x + b1.x;
        float p5 = (x1.y - mu) * rs * g1.y + b1.y;
        float p6 = (x1.z - mu) * rs * g1.z + b1.z;
        float p7 = (x1.w - mu) * rs * g1.w + b1.w;
        uint2 ua, ub;
        ua.x = pk(p0, p1); ua.y = pk(p2, p3);
        ub.x = pk(p4, p5); ub.y = pk(p6, p7);
        *(uint2*)(pn + row_l * 136 + lm * 4) = ua;
        *(uint2*)(pn + row_l * 136 + 64 + lm * 4) = ub;
    }
    __syncthreads();
    f32x4 acc[2][8];
#pragma unroll
    for (int i = 0; i < 2; i++)
#pragma unroll
        for (int j = 0; j < 8; j++) acc[i][j] = (f32x4){0.f, 0.f, 0.f, 0.f};
#pragma unroll
    for (int ks = 0; ks < 4; ks++) {
        bhalf8 af0 = *(const bhalf8*)(pn + (w * 32 + lm) * 136 + ks * 32 + lq * 8);
        bhalf8 af1 = *(const bhalf8*)(pn + (w * 32 + 16 + lm) * 136 + ks * 32 + lq * 8);
#pragma unroll
        for (int nt = 0; nt < 8; nt++) {
            bhalf8 bf = *(const bhalf8*)(Wskvt + (nt * 16 + lm) * 128 + ks * 32 + lq * 8);
            acc[0][nt] = __builtin_amdgcn_mfma_f32_16x16x32_bf16(af0, bf, acc[0][nt], 0, 0, 0);
            acc[1][nt] = __builtin_amdgcn_mfma_f32_16x16x32_bf16(af1, bf, acc[1][nt], 0, 0, 0);
        }
    }
    __syncthreads();  // pn fully consumed
#pragma unroll
    for (int nt = 0; nt < 4; nt++) {  // sk: [k][64]
        int col = nt * 16 + lm;
        float bia = bsk[col];
#pragma unroll
        for (int rt = 0; rt < 2; rt++)
#pragma unroll
            for (int r = 0; r < 4; r++)
                skl[(w * 32 + rt * 16 + lq * 4 + r) * 72 + col] = f2bf(acc[rt][nt][r] + bia);
    }
#pragma unroll
    for (int nt = 4; nt < 8; nt++) {  // svT: [d][k]
        int d = (nt - 4) * 16 + lm;
        float bia = bsv[d];
#pragma unroll
        for (int rt = 0; rt < 2; rt++) {
            int kloc = w * 32 + rt * 16 + lq * 4;
            uint2 u;
            u.x = pk(acc[rt][nt][0] + bia, acc[rt][nt][1] + bia);
            u.y = pk(acc[rt][nt][2] + bia, acc[rt][nt][3] + bia);
            *(uint2*)(svl + d * 136 + kloc) = u;
        }
    }
    __syncthreads();
#pragma unroll
    for (int i = 0; i < 4; i++) {
        int c = i * 256 + tid;
        int row = c >> 3, cg = c & 7;
        uint4 v = *(const uint4*)(skl + row * 72 + cg * 8);
        *(uint4*)(skg + ((size_t)bq * 256 + k0 + row) * 64 + cg * 8) = v;
    }
#pragma unroll
    for (int i = 0; i < 4; i++) {
        int c = i * 256 + tid;
        int d = c >> 4, cg = c & 15;
        uint4 v = *(const uint4*)(svl + d * 136 + cg * 8);
        *(uint4*)(svTg + (size_t)bq * 16384 + (size_t)d * 256 + k0 + cg * 8) = v;
    }
}

// ---------------- K4: per-(b,q) struct scores + softmax + struct-out (global-B MFMA) ----------------
__global__ __launch_bounds__(256) void k_attn(const float* __restrict__ qs,
                                              const unsigned short* __restrict__ skg,
                                              const unsigned short* __restrict__ svTg,
                                              const float* __restrict__ wg,
                                              unsigned short* __restrict__ pbf,
                                              float* __restrict__ attn) {
    __shared__ __align__(16) unsigned short Ql[16 * 72];
    __shared__ __align__(16) unsigned short A2[16 * 264];
    __shared__ float redm[16][4];
    __shared__ float reds[16][4];
    int tid = threadIdx.x;
    int bq = blockIdx.x;
    int b = bq >> 8, q = bq & 255;
    int w = tid >> 6, lane = tid & 63, lm = lane & 15, lq = lane >> 4;
    if (tid < 192) {
        int h = tid >> 4, dc = (tid & 15) * 4;
        float4 v = *(const float4*)(qs + (((size_t)b * HEADS + h) * Nn + q) * Dd + dc);
        uint2 u; u.x = pk(v.x, v.y); u.y = pk(v.z, v.w);
        *(uint2*)(Ql + h * 72 + dc) = u;
    } else {
        int t = tid - 192;
        int h = 12 + (t >> 4), dc = (t & 15) * 4;
        uint2 z; z.x = 0; z.y = 0;
        *(uint2*)(Ql + h * 72 + dc) = z;
    }
    __syncthreads();
    const unsigned short* skb = skg + (size_t)bq * 16384;
    f32x4 acc1[4];
#pragma unroll
    for (int i = 0; i < 4; i++) acc1[i] = (f32x4){0.f, 0.f, 0.f, 0.f};
#pragma unroll
    for (int ks = 0; ks < 2; ks++) {
        bhalf8 af = *(const bhalf8*)(Ql + lm * 72 + ks * 32 + lq * 8);
#pragma unroll
        for (int nt = 0; nt < 4; nt++) {
            bhalf8 bf = *(const bhalf8*)(skb + (size_t)((w * 4 + nt) * 16 + lm) * 64 + ks * 32 + lq * 8);
            acc1[nt] = __builtin_amdgcn_mfma_f32_16x16x32_bf16(af, bf, acc1[nt], 0, 0, 0);
        }
    }
    size_t wbase = ((size_t)b * HEADS) * 65536 + (size_t)q * 256;
    float S[4][4];
#pragma unroll
    for (int nt = 0; nt < 4; nt++)
#pragma unroll
        for (int r = 0; r < 4; r++) {
            int row = lq * 4 + r;
            int col = (w * 4 + nt) * 16 + lm;
            float wgv = (row < 12) ? wg[wbase + (size_t)row * 65536 + col] : 0.f;
            S[nt][r] = acc1[nt][r] + wgv;
        }
    float m4[4];
#pragma unroll
    for (int r = 0; r < 4; r++)
        m4[r] = fmaxf(fmaxf(S[0][r], S[1][r]), fmaxf(S[2][r], S[3][r]));
#pragma unroll
    for (int mk = 1; mk < 16; mk <<= 1)
#pragma unroll
        for (int r = 0; r < 4; r++) m4[r] = fmaxf(m4[r], __shfl_xor(m4[r], mk));
    if (lm == 0) {
#pragma unroll
        for (int r = 0; r < 4; r++) redm[lq * 4 + r][w] = m4[r];
    }
    __syncthreads();
    float rowmax[4];
#pragma unroll
    for (int r = 0; r < 4; r++) {
        int row = lq * 4 + r;
        rowmax[r] = fmaxf(fmaxf(redm[row][0], redm[row][1]), fmaxf(redm[row][2], redm[row][3]));
    }
    float P[4][4], psum[4];
#pragma unroll
    for (int r = 0; r < 4; r++) {
#pragma unroll
        for (int nt = 0; nt < 4; nt++) P[nt][r] = __expf(S[nt][r] - rowmax[r]);
        psum[r] = (P[0][r] + P[1][r]) + (P[2][r] + P[3][r]);
    }
#pragma unroll
    for (int mk = 1; mk < 16; mk <<= 1)
#pragma unroll
        for (int r = 0; r < 4; r++) psum[r] += __shfl_xor(psum[r], mk);
    if (lm == 0) {
#pragma unroll
        for (int r = 0; r < 4; r++) reds[lq * 4 + r][w] = psum[r];
    }
    __syncthreads();
    float inv[4];
#pragma unroll
    for (int r = 0; r < 4; r++) {
        int row = lq * 4 + r;
        inv[r] = 1.f / ((reds[row][0] + reds[row][1]) + (reds[row][2] + reds[row][3]));
    }
#pragma unroll
    for (int nt = 0; nt < 4; nt++)
#pragma unroll
        for (int r = 0; r < 4; r++) {
            int row = lq * 4 + r;
            int col = (w * 4 + nt) * 16 + lm;
            float p = P[nt][r] * inv[r];
            unsigned short pv = f2bf(p);
            A2[row * 264 + col] = pv;
            if (row < 12) pbf[wbase + (size_t)row * 65536 + col] = pv;
        }
    __syncthreads();
    const unsigned short* svb = svTg + (size_t)bq * 16384;
    f32x4 acc2 = (f32x4){0.f, 0.f, 0.f, 0.f};
#pragma unroll
    for (int ks = 0; ks < 8; ks++) {
        bhalf8 af = *(const bhalf8*)(A2 + lm * 264 + ks * 32 + lq * 8);
        bhalf8 bf = *(const bhalf8*)(svb + (size_t)(w * 16 + lm) * 256 + ks * 32 + lq * 8);
        acc2 = __builtin_amdgcn_mfma_f32_16x16x32_bf16(af, bf, acc2, 0, 0, 0);
    }
#pragma unroll
    for (int r = 0; r < 4; r++) {
        int row = lq * 4 + r;
        if (row < 12) attn[(size_t)bq * Hh + row * 64 + w * 16 + lm] = acc2[r];
    }
}

// ---------------- K5: content out = P @ V, MFMA, zero LDS, accumulate into attn ----------------
__global__ __launch_bounds__(256) void k_ctxout(const unsigned short* __restrict__ pbf,
                                                const unsigned short* __restrict__ vvT,
                                                float* __restrict__ attn) {
    int tid = threadIdx.x;
    int m0 = blockIdx.x * 64;
    int bh = blockIdx.y;
    int b = bh / HEADS, h = bh % HEADS;
    int w = tid >> 6, lane = tid & 63, lm = lane & 15, lq = lane >> 4;
    const unsigned short* Pb = pbf + (size_t)bh * 65536;
    const unsigned short* Vb = vvT + (size_t)bh * 16384;
    f32x4 acc[4];
#pragma unroll
    for (int i = 0; i < 4; i++) acc[i] = (f32x4){0.f, 0.f, 0.f, 0.f};
#pragma unroll
    for (int ks = 0; ks < 8; ks++) {
        bhalf8 af = *(const bhalf8*)(Pb + (size_t)(m0 + w * 16 + lm) * 256 + ks * 32 + lq * 8);
#pragma unroll
        for (int ct = 0; ct < 4; ct++) {
            bhalf8 bf = *(const bhalf8*)(Vb + (size_t)(ct * 16 + lm) * 256 + ks * 32 + lq * 8);
            acc[ct] = __builtin_amdgcn_mfma_f32_16x16x32_bf16(af, bf, acc[ct], 0, 0, 0);
        }
    }
#pragma unroll
    for (int ct = 0; ct < 4; ct++)
#pragma unroll
        for (int r = 0; r < 4; r++) {
            int row = m0 + w * 16 + lq * 4 + r;
            int col = h * 64 + ct * 16 + lm;
            size_t o = ((size_t)b * Nn + row) * Hh + col;
            attn[o] += acc[ct][r];
        }
}

// ---------------- K6: out projection + bias + relu + residual; dbuf-A, global-B ----------------
__global__ __launch_bounds__(256) void k_outproj(const float* __restrict__ attn,
                                                 const unsigned short* __restrict__ Wot, // [768][768] n-major
                                                 const float* __restrict__ bo,
                                                 const float* __restrict__ nodes,
                                                 float* __restrict__ tmp) {
    __shared__ __align__(16) unsigned short A[2][64 * 72];
    int tid = threadIdx.x;
    int m0 = blockIdx.y * 64;
    int n0 = blockIdx.x * 128;
    int w = tid >> 6, lane = tid & 63;
    int wm = w >> 1, wn = w & 1;
    int lm = lane & 15, lq = lane >> 4;
    auto stageA = [&](int kt, unsigned short* dst) {
#pragma unroll
        for (int t = 0; t < 4; t++) {
            int c = t * 256 + tid;
            int row = c >> 4, cc = c & 15;
            float4 v = *(const float4*)(attn + (size_t)(m0 + row) * 768 + kt + cc * 4);
            uint2 u; u.x = pk(v.x, v.y); u.y = pk(v.z, v.w);
            *(uint2*)(dst + row * 72 + cc * 4) = u;
        }
    };
    f32x4 acc[2][4];
#pragma unroll
    for (int i = 0; i < 2; i++)
#pragma unroll
        for (int j = 0; j < 4; j++) acc[i][j] = (f32x4){0.f, 0.f, 0.f, 0.f};
    stageA(0, A[0]);
    __syncthreads();
    int buf = 0;
    for (int kt = 0; kt < 768; kt += 64, buf ^= 1) {
        if (kt < 704) stageA(kt + 64, A[buf ^ 1]);
#pragma unroll
        for (int ks = 0; ks < 2; ks++) {
            bhalf8 af[2];
#pragma unroll
            for (int mi = 0; mi < 2; mi++)
                af[mi] = *(const bhalf8*)(A[buf] + (wm * 32 + mi * 16 + lm) * 72 + ks * 32 + lq * 8);
#pragma unroll
            for (int nt = 0; nt < 4; nt++) {
                bhalf8 bf = *(const bhalf8*)(Wot + (size_t)(n0 + wn * 64 + nt * 16 + lm) * 768 + kt + ks * 32 + lq * 8);
#pragma unroll
                for (int mi = 0; mi < 2; mi++)
                    acc[mi][nt] = __builtin_amdgcn_mfma_f32_16x16x32_bf16(af[mi], bf, acc[mi][nt], 0, 0, 0);
            }
        }
        __syncthreads();
    }
#pragma unroll
    for (int mi = 0; mi < 2; mi++)
#pragma unroll
        for (int nt = 0; nt < 4; nt++)
#pragma unroll
            for (int r = 0; r < 4; r++) {
                int row = m0 + wm * 32 + mi * 16 + lq * 4 + r;
                int col = n0 + wn * 64 + nt * 16 + lm;
                float val = acc[mi][nt][r] + bo[col];
                val = fmaxf(val, 0.f) + nodes[(size_t)row * 768 + col];
                tmp[(size_t)row * 768 + col] = val;
            }
}

// ---------------- K7: final row LayerNorm ----------------
__global__ __launch_bounds__(256) void k_finalln(const float* __restrict__ tmp,
                                                 const float* __restrict__ go,
                                                 const float* __restrict__ bout,
                                                 float* __restrict__ out) {
    __shared__ float rs1[4], rs2[4];
    int m = blockIdx.x, tid = threadIdx.x;
    int lane = tid & 63, wid = tid >> 6;
    const float* row = tmp + (size_t)m * 768;
    float x0 = row[tid], x1 = row[tid + 256], x2 = row[tid + 512];
    float s = x0 + x1 + x2;
    float s2 = x0 * x0 + x1 * x1 + x2 * x2;
#pragma unroll
    for (int mk = 32; mk; mk >>= 1) {
        s += __shfl_xor(s, mk);
        s2 += __shfl_xor(s2, mk);
    }
    if (lane == 0) { rs1[wid] = s; rs2[wid] = s2; }
    __syncthreads();
    s = rs1[0] + rs1[1] + rs1[2] + rs1[3];
    s2 = rs2[0] + rs2[1] + rs2[2] + rs2[3];
    float mu = s * (1.f / 768.f);
    float var = s2 * (1.f / 768.f) - mu * mu;
    float rstd = rsqrtf(var + EPSf);
    float* orow = out + (size_t)m * 768;
    orow[tid] = (x0 - mu) * rstd * go[tid] + bout[tid];
    orow[tid + 256] = (x1 - mu) * rstd * go[tid + 256] + bout[tid + 256];
    orow[tid + 512] = (x2 - mu) * rstd * go[tid + 512] + bout[tid + 512];
}

extern "C" void kernel_launch(void* const* d_in, const int* in_sizes, int n_in,
                              void* d_out, int out_size, void* d_ws, size_t ws_size,
                              hipStream_t stream) {
    const float* nodes = (const float*)d_in[0];
    const float* bias  = (const float*)d_in[1];
    const float* paths = (const float*)d_in[2];
    const float* Wq = (const float*)d_in[3];  const float* bq  = (const float*)d_in[4];
    const float* Wk = (const float*)d_in[5];  const float* bk  = (const float*)d_in[6];
    const float* Wv = (const float*)d_in[7];  const float* bv  = (const float*)d_in[8];
    const float* Wsk = (const float*)d_in[9]; const float* bsk = (const float*)d_in[10];
    const float* Wsv = (const float*)d_in[11];const float* bsv = (const float*)d_in[12];
    const float* Wo = (const float*)d_in[13]; const float* bo  = (const float*)d_in[14];
    const float* gp = (const float*)d_in[15]; const float* bp  = (const float*)d_in[16];
    const float* go = (const float*)d_in[17]; const float* bout= (const float*)d_in[18];
    float* out = (float*)d_out;

    char* ws = (char*)d_ws;
    size_t off = 0;
    auto carve = [&](size_t bytes) -> char* {
        char* p = ws + off;
        off += (bytes + 255) & ~(size_t)255;
        return p;
    };
    float* qs   = (float*)carve((size_t)Bb * HEADS * Nn * Dd * 4);
    float* kk   = (float*)carve((size_t)Bb * HEADS * Nn * Dd * 4);
    float* wg   = (float*)carve((size_t)Bb * HEADS * Nn * Nn * 4);
    float* attn = (float*)carve((size_t)Bb * Nn * Hh * 4);
    float* tmp  = (float*)carve((size_t)Bb * Nn * Hh * 4);
    unsigned short* Wqkvt = (unsigned short*)carve((size_t)3 * 768 * 768 * 2);
    unsigned short* Wot   = (unsigned short*)carve((size_t)768 * 768 * 2);
    unsigned short* Wskvt = (unsigned short*)carve((size_t)128 * 128 * 2);
    unsigned short* vvT   = (unsigned short*)carve((size_t)Bb * HEADS * Dd * Nn * 2);
    unsigned short* pbf   = (unsigned short*)carve((size_t)Bb * HEADS * Nn * Nn * 2);
    unsigned short* skg   = (unsigned short*)carve((size_t)Bb * Nn * Nn * Dd * 2);
    unsigned short* svTg  = (unsigned short*)carve((size_t)Bb * Nn * Dd * Nn * 2);
    (void)ws_size; (void)in_sizes; (void)n_in; (void)out_size;

    hipLaunchKernelGGL(k_transpose4, dim3(24, 24, 4), dim3(256), 0, stream,
                       Wq, Wk, Wv, Wo,
                       Wqkvt, Wqkvt + (size_t)768 * 768, Wqkvt + (size_t)2 * 768 * 768, Wot);
    hipLaunchKernelGGL(k_transpose_small, dim3(2, 4, 2), dim3(256), 0, stream,
                       Wsk, Wsv, Wskvt, Wskvt + (size_t)64 * 128);

    hipLaunchKernelGGL(k_qkv, dim3(18, 32), dim3(256), 0, stream, nodes, Wqkvt, bq, bk, bv, qs, kk, vvT);
    hipLaunchKernelGGL(k_scores, dim3(4, 4, 96), dim3(256), 0, stream, qs, kk, bias, wg);
    hipLaunchKernelGGL(k_structproj, dim3(4096), dim3(256), 0, stream, paths, Wskvt, gp, bp, bsk, bsv, skg, svTg);
    hipLaunchKernelGGL(k_attn, dim3(2048), dim3(256), 0, stream, qs, skg, svTg, wg, pbf, attn);
    hipLaunchKernelGGL(k_ctxout, dim3(4, 96), dim3(256), 0, stream, pbf, vvT, attn);
    hipLaunchKernelGGL(k_outproj, dim3(6, 32), dim3(256), 0, stream, attn, Wot, bo, nodes, tmp);
    hipLaunchKernelGGL(k_finalln, dim3(2048), dim3(256), 0, stream, tmp, go, bout, out);
}